// Round 2
// baseline (612.316 us; speedup 1.0000x reference)
//
#include <hip/hip_runtime.h>

#define LQ 300
#define NB 32
#define SK 1024
#define EE 256
#define HH 8
#define DH 32
#define BH 256   // N*H
#define LPAD 304
#define NLB 5    // ceil(300/64) 64-row L-blocks per head

typedef short short8 __attribute__((ext_vector_type(8)));
typedef short short4v __attribute__((ext_vector_type(4)));
typedef float f32x4 __attribute__((ext_vector_type(4)));

#define MFMA16(a, b, c) __builtin_amdgcn_mfma_f32_16x16x32_bf16((a), (b), (c), 0, 0, 0)

__device__ __forceinline__ short f2bf(float f) {
    unsigned u = __float_as_uint(f);
    u += 0x7FFFu + ((u >> 16) & 1u);   // round-to-nearest-even
    return (short)(u >> 16);
}

__device__ __forceinline__ short8 cvt8(const float* __restrict__ p) {
    float4 x = *(const float4*)p;
    float4 y = *(const float4*)(p + 4);
    short8 r;
    r[0] = f2bf(x.x); r[1] = f2bf(x.y); r[2] = f2bf(x.z); r[3] = f2bf(x.w);
    r[4] = f2bf(y.x); r[5] = f2bf(y.y); r[6] = f2bf(y.z); r[7] = f2bf(y.w);
    return r;
}

// ---------------------------------------------------------------------------
// prep: convert in_proj_weight (3E x E) + out_proj_weight (E x E) to bf16
// ---------------------------------------------------------------------------
__global__ __launch_bounds__(256) void prep_kernel(
    const float* __restrict__ ipw, const float* __restrict__ opw,
    short* __restrict__ wbf)
{
    int i = blockIdx.x * 256 + threadIdx.x;   // 0..65535
    int base = i * 4;
    const float* src = (base < 3 * EE * EE) ? (ipw + base) : (opw + base - 3 * EE * EE);
    float4 x = *(const float4*)src;
    short4v r;
    r[0] = f2bf(x.x); r[1] = f2bf(x.y); r[2] = f2bf(x.z); r[3] = f2bf(x.w);
    *(short4v*)(wbf + base) = r;
}

// ---------------------------------------------------------------------------
// QKV projection: wave = 16 tokens x ALL 256 features, K=256. X read once.
// ---------------------------------------------------------------------------
__global__ __launch_bounds__(256) void proj_kernel(
    const float* __restrict__ query, const float* __restrict__ key,
    const float* __restrict__ value, const short* __restrict__ wbf,
    const float* __restrict__ bias,
    short* __restrict__ qws, short* __restrict__ kws, short* __restrict__ vws)
{
    int wave = (blockIdx.x * 256 + threadIdx.x) >> 6;
    int lid = threadIdx.x & 63, quad = lid >> 4, l16 = lid & 15;

    int u = wave, p;
    const float* X;
    if (u < 600)             { p = 0; X = query; }
    else if (u < 600 + 2048) { p = 1; X = key;   u -= 600; }
    else                     { p = 2; X = value; u -= 2648; }
    int t = u * 16 + l16;

    const short* wb = wbf + p * EE * EE;
    f32x4 acc[16];
    #pragma unroll
    for (int f = 0; f < 16; f++) acc[f] = (f32x4){0.f, 0.f, 0.f, 0.f};

    for (int ks = 0; ks < 8; ks++) {
        short8 af = cvt8(X + (size_t)t * EE + ks * 32 + quad * 8);
        #pragma unroll
        for (int f = 0; f < 16; f++) {
            short8 bf = *(const short8*)(wb + (size_t)(f * 16 + l16) * EE + ks * 32 + quad * 8);
            acc[f] = MFMA16(af, bf, acc[f]);
        }
    }

    int tokbase = (wave < 600 ? wave : u) * 16;   // token group base within its matrix
    #pragma unroll
    for (int f = 0; f < 16; f++) {
        int feat = f * 16 + l16;
        float bia = bias[p * EE + feat];
        int h = feat >> 5, d = feat & 31;
        #pragma unroll
        for (int r = 0; r < 4; r++) {
            int tok = tokbase + quad * 4 + r;
            float v = acc[f][r] + bia;
            int n = tok & 31, s = tok >> 5;
            int b = n * HH + h;
            if (p == 0) {
                v *= 0.17677669529663687f;   // Dh^-0.5
                qws[((size_t)b * LPAD + s) * DH + d] = f2bf(v);
            } else if (p == 1) {
                kws[((size_t)b * SK + s) * DH + d] = f2bf(v);
            } else {
                vws[((size_t)b * SK + s) * DH + d] = f2bf(v);
            }
        }
    }
}

// ---------------------------------------------------------------------------
// V transpose: vt[b][d][s] from vws[b][s][d], LDS tiled, coalesced both sides
// ---------------------------------------------------------------------------
__global__ __launch_bounds__(256) void vtrans_kernel(
    const short* __restrict__ vws, short* __restrict__ vt)
{
    __shared__ __align__(16) short tile[32][272];   // 272: 16B-aligned rows
    int b = blockIdx.x >> 2, s0 = (blockIdx.x & 3) * 256;
    const short* src = vws + ((size_t)b * SK + s0) * DH;
    #pragma unroll
    for (int pass = 0; pass < 4; pass++) {
        int i = pass * 256 + threadIdx.x;
        int sl = i >> 2, d0 = (i & 3) * 8;
        short8 x = *(const short8*)(src + sl * DH + d0);
        #pragma unroll
        for (int j = 0; j < 8; j++) tile[d0 + j][sl] = x[j];
    }
    __syncthreads();
    short* dst = vt + (size_t)b * DH * SK + s0;
    #pragma unroll
    for (int pass = 0; pass < 4; pass++) {
        int i = pass * 256 + threadIdx.x;
        int d = i >> 5, sl0 = (i & 31) * 8;
        *(short8*)(dst + (size_t)d * SK + sl0) = *(const short8*)(&tile[d][sl0]);
    }
}

// ---------------------------------------------------------------------------
// Flash attention v2: block = (head, 64 L-rows); each of 4 waves owns 16
// complete rows x full S=1024 (16 chunks of 64). No cross-wave merge.
// K/V re-read factor drops 19x -> 5x; waves of a block share K/V chunks (L1).
// A-domain softmax: raw QK round-trips LDS (C-layout write -> A-layout read);
// gauss + mask applied in A-domain with vectorized loads; defer-max rescale.
// ---------------------------------------------------------------------------
__global__ __launch_bounds__(256) void attn_kernel(
    const short* __restrict__ qws, const short* __restrict__ kws,
    const short* __restrict__ vt, const float* __restrict__ gauss,
    const unsigned char* __restrict__ mask, short* __restrict__ ows)
{
    __shared__ __align__(16) float smem[4][16 * 64];   // per-wave fp32 S-tile

    // XCD-aware bijective swizzle: 1280 blocks = 8 XCDs x 160 contiguous;
    // the 5 L-blocks of one head are consecutive -> co-scheduled, K/V L2-warm.
    int bid = blockIdx.x;
    int swzb = (bid & 7) * ((BH * NLB) >> 3) + (bid >> 3);
    int b = swzb / NLB, lt = swzb % NLB;

    int wv = threadIdx.x >> 6;
    int lid = threadIdx.x & 63, quad = lid >> 4, l16 = lid & 15;
    int n = b >> 3, h = b & 7;

    int l0 = lt * 64 + wv * 16;               // wave's first L row
    int qrow = l0 + l16; if (qrow > LPAD - 1) qrow = LPAD - 1;   // tail clamp
    short8 qa = *(const short8*)(qws + ((size_t)b * LPAD + qrow) * DH + quad * 8);

    int grow = l0 + l16; if (grow > LQ - 1) grow = LQ - 1;
    const float* gl = gauss + ((size_t)b * LQ + grow) * SK;
    const unsigned char* mrow = mask + (size_t)n * SK;

    f32x4 o0 = {0.f, 0.f, 0.f, 0.f}, o1 = {0.f, 0.f, 0.f, 0.f};
    float mr = -3e38f, ls = 0.f;              // running stats for row l0+l16

    float* sl = smem[wv];
    // read-side swizzled float offsets (row = l16, 16B-aligned b128 chunks)
    int rk = l16 & 7;
    int ra0 = l16 * 64 + (((quad * 2 + 0) ^ rk) << 2);
    int ra1 = l16 * 64 + (((quad * 2 + 1) ^ rk) << 2);
    int ra2 = l16 * 64 + (((quad * 2 + 8) ^ rk) << 2);
    int ra3 = l16 * 64 + (((quad * 2 + 9) ^ rk) << 2);

    for (int it = 0; it < 16; it++) {
        int sc = it * 64;

        short8 kb[4];
        #pragma unroll
        for (int c = 0; c < 4; c++)
            kb[c] = *(const short8*)(kws + ((size_t)b * SK + sc + c * 16 + l16) * DH + quad * 8);

        short8 vb[2][2];
        #pragma unroll
        for (int t2 = 0; t2 < 2; t2++)
            #pragma unroll
            for (int k2 = 0; k2 < 2; k2++)
                vb[t2][k2] = *(const short8*)(vt + ((size_t)b * DH + t2 * 16 + l16) * SK + sc + k2 * 32 + quad * 8);

        // A-domain gauss: lane's own row, cols quad*8..+7 and 32+quad*8..+7
        f32x4 g0 = *(const f32x4*)(gl + sc + quad * 8);
        f32x4 g1 = *(const f32x4*)(gl + sc + quad * 8 + 4);
        f32x4 g2 = *(const f32x4*)(gl + sc + 32 + quad * 8);
        f32x4 g3 = *(const f32x4*)(gl + sc + 32 + quad * 8 + 4);

        // A-domain mask bytes for the same cols
        const unsigned* mp0 = (const unsigned*)(mrow + sc + quad * 8);
        unsigned mk0 = mp0[0], mk1 = mp0[1];
        const unsigned* mp1 = (const unsigned*)(mrow + sc + 32 + quad * 8);
        unsigned mk2 = mp1[0], mk3 = mp1[1];

        f32x4 z = {0.f, 0.f, 0.f, 0.f};
        f32x4 cc[4];
        #pragma unroll
        for (int c = 0; c < 4; c++) cc[c] = MFMA16(qa, kb[c], z);

        // C-domain: raw QK scores -> swizzled LDS (2-way write banks, b128 reads)
        #pragma unroll
        for (int r = 0; r < 4; r++) {
            int row = quad * 4 + r;
            int rowoff = row * 64;
            int rkw = row & 7;
            #pragma unroll
            for (int c = 0; c < 4; c++) {
                int colg = c * 4 + (l16 >> 2);
                sl[rowoff + (((colg ^ rkw) << 2) + (l16 & 3))] = cc[c][r];
            }
        }

        asm volatile("s_waitcnt lgkmcnt(0)" ::: "memory");

        f32x4 s0 = *(const f32x4*)(sl + ra0);
        f32x4 s1 = *(const f32x4*)(sl + ra1);
        f32x4 s2 = *(const f32x4*)(sl + ra2);
        f32x4 s3 = *(const f32x4*)(sl + ra3);

        // add gauss / apply mask in A-domain
        #pragma unroll
        for (int j = 0; j < 4; j++) {
            s0[j] = ((mk0 >> (8 * j)) & 0xffu) ? -3e38f : (s0[j] + g0[j]);
            s1[j] = ((mk1 >> (8 * j)) & 0xffu) ? -3e38f : (s1[j] + g1[j]);
            s2[j] = ((mk2 >> (8 * j)) & 0xffu) ? -3e38f : (s2[j] + g2[j]);
            s3[j] = ((mk3 >> (8 * j)) & 0xffu) ? -3e38f : (s3[j] + g3[j]);
        }

        // row max: 15 local + 2 shfl (row spans the 4 quads)
        float mxa = fmaxf(fmaxf(fmaxf(s0[0], s0[1]), fmaxf(s0[2], s0[3])),
                          fmaxf(fmaxf(s1[0], s1[1]), fmaxf(s1[2], s1[3])));
        float mxb = fmaxf(fmaxf(fmaxf(s2[0], s2[1]), fmaxf(s2[2], s2[3])),
                          fmaxf(fmaxf(s3[0], s3[1]), fmaxf(s3[2], s3[3])));
        float mx = fmaxf(mxa, mxb);
        mx = fmaxf(mx, __shfl_xor(mx, 16, 64));
        mx = fmaxf(mx, __shfl_xor(mx, 32, 64));

        // defer-max: only rescale when the wave's max grew by > 8
        if (!__all(mx <= mr + 8.f)) {
            float nm = fmaxf(mr, mx);
            float al = __expf(mr - nm);
            mr = nm;
            ls *= al;
            int albits = __float_as_int(al);
            #pragma unroll
            for (int r = 0; r < 4; r++) {
                float alr = __int_as_float(
                    __builtin_amdgcn_ds_bpermute(4 * (quad * 4 + r), albits));
                o0[r] *= alr;
                o1[r] *= alr;
            }
        }

        float p[16];
        #pragma unroll
        for (int j = 0; j < 4; j++) {
            p[j]      = __expf(s0[j] - mr);
            p[4 + j]  = __expf(s1[j] - mr);
            p[8 + j]  = __expf(s2[j] - mr);
            p[12 + j] = __expf(s3[j] - mr);
        }
        float sm = 0.f;
        #pragma unroll
        for (int j = 0; j < 16; j++) sm += p[j];
        sm += __shfl_xor(sm, 16, 64);
        sm += __shfl_xor(sm, 32, 64);
        ls += sm;

        // pack P to bf16 A-fragments in-register
        short8 pa0, pa1;
        #pragma unroll
        for (int j = 0; j < 4; j++) {
            pa0[j]     = f2bf(p[j]);
            pa0[4 + j] = f2bf(p[4 + j]);
            pa1[j]     = f2bf(p[8 + j]);
            pa1[4 + j] = f2bf(p[12 + j]);
        }

        o0 = MFMA16(pa0, vb[0][0], o0);
        o0 = MFMA16(pa1, vb[0][1], o0);
        o1 = MFMA16(pa0, vb[1][0], o1);
        o1 = MFMA16(pa1, vb[1][1], o1);
    }

    // epilogue: per-wave normalize + store (no cross-wave merge)
    float inv = 1.0f / ls;                   // per-row (lane l16 holds its row)
    int invbits = __float_as_int(inv);
    #pragma unroll
    for (int r = 0; r < 4; r++) {
        float invr = __int_as_float(
            __builtin_amdgcn_ds_bpermute(4 * (quad * 4 + r), invbits));
        int l = l0 + quad * 4 + r;
        if (l < LQ) {
            size_t base = ((size_t)l * NB + n) * EE + h * DH;
            ows[base + l16]      = f2bf(o0[r] * invr);
            ows[base + 16 + l16] = f2bf(o1[r] * invr);
        }
    }
}

// ---------------------------------------------------------------------------
// Output projection: wave = 16 tokens x 256 features, bf16 A/B, fp32 out
// ---------------------------------------------------------------------------
__global__ __launch_bounds__(256) void oproj_kernel(
    const short* __restrict__ xa, const short* __restrict__ wbf,
    const float* __restrict__ bias, float* __restrict__ out)
{
    int wave = (blockIdx.x * 256 + threadIdx.x) >> 6;
    int lid = threadIdx.x & 63, quad = lid >> 4, l16 = lid & 15;
    int t = wave * 16 + l16;

    const short* wb = wbf + 3 * EE * EE;
    f32x4 acc[16];
    #pragma unroll
    for (int f = 0; f < 16; f++) acc[f] = (f32x4){0.f, 0.f, 0.f, 0.f};

    for (int ks = 0; ks < 8; ks++) {
        short8 af = *(const short8*)(xa + (size_t)t * EE + ks * 32 + quad * 8);
        #pragma unroll
        for (int f = 0; f < 16; f++) {
            short8 bf = *(const short8*)(wb + (size_t)(f * 16 + l16) * EE + ks * 32 + quad * 8);
            acc[f] = MFMA16(af, bf, acc[f]);
        }
    }

    #pragma unroll
    for (int f = 0; f < 16; f++) {
        int e = f * 16 + l16;
        float bi = bias[e];
        #pragma unroll
        for (int r = 0; r < 4; r++) {
            int tok = wave * 16 + quad * 4 + r;
            out[(size_t)tok * EE + e] = acc[f][r] + bi;
        }
    }
}

extern "C" void kernel_launch(void* const* d_in, const int* in_sizes, int n_in,
                              void* d_out, int out_size, void* d_ws, size_t ws_size,
                              hipStream_t stream) {
    const float* query = (const float*)d_in[0];
    const float* key   = (const float*)d_in[1];
    const float* value = (const float*)d_in[2];
    const float* gauss = (const float*)d_in[3];
    const unsigned char* mask = (const unsigned char*)d_in[4];
    const float* ipw = (const float*)d_in[5];
    const float* ipb = (const float*)d_in[6];
    const float* opw = (const float*)d_in[7];
    const float* opb = (const float*)d_in[8];
    float* out = (float*)d_out;

    short* wbf = (short*)d_ws;                        // 262144 shorts
    short* qws = wbf + 4 * EE * EE;                   // 256*304*32
    short* kws = qws + (size_t)BH * LPAD * DH;        // 256*1024*32
    short* vws = kws + (size_t)BH * SK * DH;          // 256*1024*32
    short* vt  = vws + (size_t)BH * SK * DH;          // 256*32*1024
    short* ows = vt  + (size_t)BH * SK * DH;          // 9600*256

    prep_kernel<<<256, 256, 0, stream>>>(ipw, opw, wbf);
    proj_kernel<<<1174, 256, 0, stream>>>(query, key, value, wbf, ipb, qws, kws, vws);
    vtrans_kernel<<<1024, 256, 0, stream>>>(vws, vt);
    attn_kernel<<<BH * NLB, 256, 0, stream>>>(qws, kws, vt, gauss, mask, ows);
    oproj_kernel<<<150, 256, 0, stream>>>(ows, wbf, opb, out);
}

// Round 4
// 593.431 us; speedup vs baseline: 1.0318x; 1.0318x over previous
//
#include <hip/hip_runtime.h>

#define LQ 300
#define NB 32
#define SK 1024
#define EE 256
#define HH 8
#define DH 32
#define BH 256   // N*H
#define LPAD 304
#define NLT 19   // ceil(300/16)

typedef short short8 __attribute__((ext_vector_type(8)));
typedef short short4v __attribute__((ext_vector_type(4)));
typedef float f32x4 __attribute__((ext_vector_type(4)));

#define MFMA16(a, b, c) __builtin_amdgcn_mfma_f32_16x16x32_bf16((a), (b), (c), 0, 0, 0)

__device__ __forceinline__ short f2bf(float f) {
    unsigned u = __float_as_uint(f);
    u += 0x7FFFu + ((u >> 16) & 1u);   // round-to-nearest-even
    return (short)(u >> 16);
}

__device__ __forceinline__ short8 cvt8(const float* __restrict__ p) {
    float4 x = *(const float4*)p;
    float4 y = *(const float4*)(p + 4);
    short8 r;
    r[0] = f2bf(x.x); r[1] = f2bf(x.y); r[2] = f2bf(x.z); r[3] = f2bf(x.w);
    r[4] = f2bf(y.x); r[5] = f2bf(y.y); r[6] = f2bf(y.z); r[7] = f2bf(y.w);
    return r;
}

// ---------------------------------------------------------------------------
// prep: convert in_proj_weight (3E x E) + out_proj_weight (E x E) to bf16
// ---------------------------------------------------------------------------
__global__ __launch_bounds__(256) void prep_kernel(
    const float* __restrict__ ipw, const float* __restrict__ opw,
    short* __restrict__ wbf)
{
    int i = blockIdx.x * 256 + threadIdx.x;   // 0..65535
    int base = i * 4;
    const float* src = (base < 3 * EE * EE) ? (ipw + base) : (opw + base - 3 * EE * EE);
    float4 x = *(const float4*)src;
    short4v r;
    r[0] = f2bf(x.x); r[1] = f2bf(x.y); r[2] = f2bf(x.z); r[3] = f2bf(x.w);
    *(short4v*)(wbf + base) = r;
}

// ---------------------------------------------------------------------------
// QKV projection: wave = 16 tokens x ALL 256 features, K=256. X read once.
// ---------------------------------------------------------------------------
__global__ __launch_bounds__(256) void proj_kernel(
    const float* __restrict__ query, const float* __restrict__ key,
    const float* __restrict__ value, const short* __restrict__ wbf,
    const float* __restrict__ bias,
    short* __restrict__ qws, short* __restrict__ kws, short* __restrict__ vws)
{
    int wave = (blockIdx.x * 256 + threadIdx.x) >> 6;
    int lid = threadIdx.x & 63, quad = lid >> 4, l16 = lid & 15;

    int u = wave, p;
    const float* X;
    if (u < 600)             { p = 0; X = query; }
    else if (u < 600 + 2048) { p = 1; X = key;   u -= 600; }
    else                     { p = 2; X = value; u -= 2648; }
    int t = u * 16 + l16;

    const short* wb = wbf + p * EE * EE;
    f32x4 acc[16];
    #pragma unroll
    for (int f = 0; f < 16; f++) acc[f] = (f32x4){0.f, 0.f, 0.f, 0.f};

    for (int ks = 0; ks < 8; ks++) {
        short8 af = cvt8(X + (size_t)t * EE + ks * 32 + quad * 8);
        #pragma unroll
        for (int f = 0; f < 16; f++) {
            short8 bf = *(const short8*)(wb + (size_t)(f * 16 + l16) * EE + ks * 32 + quad * 8);
            acc[f] = MFMA16(af, bf, acc[f]);
        }
    }

    int tokbase = (wave < 600 ? wave : u) * 16;   // token group base within its matrix
    #pragma unroll
    for (int f = 0; f < 16; f++) {
        int feat = f * 16 + l16;
        float bia = bias[p * EE + feat];
        int h = feat >> 5, d = feat & 31;
        #pragma unroll
        for (int r = 0; r < 4; r++) {
            int tok = tokbase + quad * 4 + r;
            float v = acc[f][r] + bia;
            int n = tok & 31, s = tok >> 5;
            int b = n * HH + h;
            if (p == 0) {
                v *= 0.17677669529663687f;   // Dh^-0.5
                qws[((size_t)b * LPAD + s) * DH + d] = f2bf(v);
            } else if (p == 1) {
                kws[((size_t)b * SK + s) * DH + d] = f2bf(v);
            } else {
                vws[((size_t)b * SK + s) * DH + d] = f2bf(v);
            }
        }
    }
}

// ---------------------------------------------------------------------------
// V transpose: vt[b][d][s] from vws[b][s][d], LDS tiled, coalesced both sides
// ---------------------------------------------------------------------------
__global__ __launch_bounds__(256) void vtrans_kernel(
    const short* __restrict__ vws, short* __restrict__ vt)
{
    __shared__ __align__(16) short tile[32][272];   // 272: 16B-aligned rows
    int b = blockIdx.x >> 2, s0 = (blockIdx.x & 3) * 256;
    const short* src = vws + ((size_t)b * SK + s0) * DH;
    #pragma unroll
    for (int pass = 0; pass < 4; pass++) {
        int i = pass * 256 + threadIdx.x;
        int sl = i >> 2, d0 = (i & 3) * 8;
        short8 x = *(const short8*)(src + sl * DH + d0);
        #pragma unroll
        for (int j = 0; j < 8; j++) tile[d0 + j][sl] = x[j];
    }
    __syncthreads();
    short* dst = vt + (size_t)b * DH * SK + s0;
    #pragma unroll
    for (int pass = 0; pass < 4; pass++) {
        int i = pass * 256 + threadIdx.x;
        int d = i >> 5, sl0 = (i & 31) * 8;
        *(short8*)(dst + (size_t)d * SK + sl0) = *(const short8*)(&tile[d][sl0]);
    }
}

// ---------------------------------------------------------------------------
// Flash attention v3: R1 grid (block = (b, 16-row L-tile), 4 waves split S,
// LDS flash-merge) + A-domain softmax with vectorized gauss/mask loads,
// defer-max rescale, and depth-1 gauss prefetch hiding HBM latency under
// softmax+PV of the previous chunk.
// ---------------------------------------------------------------------------
__global__ __launch_bounds__(256) void attn_kernel(
    const short* __restrict__ qws, const short* __restrict__ kws,
    const short* __restrict__ vt, const float* __restrict__ gauss,
    const unsigned char* __restrict__ mask, short* __restrict__ ows)
{
    // smem[wv]: fp32 S-tile (16x64, XOR-swizzled) in the loop; reused as the
    // 16x32 O-partial buffer in the epilogue.
    __shared__ __align__(16) float smem[4][16 * 64];
    __shared__ float mbuf[4][16];
    __shared__ float lbuf[4][16];

    // XCD-aware bijective swizzle: 4864 = 8 x 608
    int bid = blockIdx.x;
    int swzb = (bid & 7) * ((BH * NLT) >> 3) + (bid >> 3);
    int b = swzb / NLT, lt = swzb % NLT;

    int wv = threadIdx.x >> 6;
    int lid = threadIdx.x & 63, quad = lid >> 4, l16 = lid & 15;
    int n = b >> 3, h = b & 7;

    int ql = lt * 16 + l16;                   // < 304, in-bounds of qws
    short8 qa = *(const short8*)(qws + ((size_t)b * LPAD + ql) * DH + quad * 8);

    int grow = lt * 16 + l16; if (grow > LQ - 1) grow = LQ - 1;
    const float* gl = gauss + ((size_t)b * LQ + grow) * SK;
    const unsigned char* mrow = mask + (size_t)n * SK;

    f32x4 o0 = {0.f, 0.f, 0.f, 0.f}, o1 = {0.f, 0.f, 0.f, 0.f};
    float mr = -3e38f, ls = 0.f;              // running stats for row lt*16+l16

    float* sl = smem[wv];
    int sbase = wv * 256;

    // read-side swizzled float offsets (row = l16, 16B-aligned b128 chunks)
    int rk = l16 & 7;
    int ra0 = l16 * 64 + (((quad * 2 + 0) ^ rk) << 2);
    int ra1 = l16 * 64 + (((quad * 2 + 1) ^ rk) << 2);
    int ra2 = l16 * 64 + (((quad * 2 + 8) ^ rk) << 2);
    int ra3 = l16 * 64 + (((quad * 2 + 9) ^ rk) << 2);

    // preload gauss + mask for chunk 0 (A-domain: own row, cols quad*8..)
    f32x4 g0 = *(const f32x4*)(gl + sbase + quad * 8);
    f32x4 g1 = *(const f32x4*)(gl + sbase + quad * 8 + 4);
    f32x4 g2 = *(const f32x4*)(gl + sbase + 32 + quad * 8);
    f32x4 g3 = *(const f32x4*)(gl + sbase + 32 + quad * 8 + 4);
    unsigned mk0 = ((const unsigned*)(mrow + sbase + quad * 8))[0];
    unsigned mk1 = ((const unsigned*)(mrow + sbase + quad * 8))[1];
    unsigned mk2 = ((const unsigned*)(mrow + sbase + 32 + quad * 8))[0];
    unsigned mk3 = ((const unsigned*)(mrow + sbase + 32 + quad * 8))[1];

    #pragma unroll
    for (int it = 0; it < 4; it++) {
        int sc = sbase + it * 64;

        short8 kb[4];
        #pragma unroll
        for (int c = 0; c < 4; c++)
            kb[c] = *(const short8*)(kws + ((size_t)b * SK + sc + c * 16 + l16) * DH + quad * 8);

        short8 vb[2][2];
        #pragma unroll
        for (int t2 = 0; t2 < 2; t2++)
            #pragma unroll
            for (int k2 = 0; k2 < 2; k2++)
                vb[t2][k2] = *(const short8*)(vt + ((size_t)b * DH + t2 * 16 + l16) * SK + sc + k2 * 32 + quad * 8);

        f32x4 z = {0.f, 0.f, 0.f, 0.f};
        f32x4 cc[4];
        #pragma unroll
        for (int c = 0; c < 4; c++) cc[c] = MFMA16(qa, kb[c], z);

        // C-domain: raw QK scores -> swizzled LDS (2-way write banks, b128 reads)
        #pragma unroll
        for (int r = 0; r < 4; r++) {
            int row = quad * 4 + r;
            int rowoff = row * 64;
            int rkw = row & 7;
            #pragma unroll
            for (int c = 0; c < 4; c++) {
                int colg = c * 4 + (l16 >> 2);
                sl[rowoff + (((colg ^ rkw) << 2) + (l16 & 3))] = cc[c][r];
            }
        }

        asm volatile("s_waitcnt lgkmcnt(0)" ::: "memory");

        f32x4 s0 = *(const f32x4*)(sl + ra0);
        f32x4 s1 = *(const f32x4*)(sl + ra1);
        f32x4 s2 = *(const f32x4*)(sl + ra2);
        f32x4 s3 = *(const f32x4*)(sl + ra3);

        // prefetch next chunk's gauss + mask (latency hides under softmax+PV)
        int itn = (it + 1) & 3;
        int scn = sbase + itn * 64;
        f32x4 h0 = *(const f32x4*)(gl + scn + quad * 8);
        f32x4 h1 = *(const f32x4*)(gl + scn + quad * 8 + 4);
        f32x4 h2 = *(const f32x4*)(gl + scn + 32 + quad * 8);
        f32x4 h3 = *(const f32x4*)(gl + scn + 32 + quad * 8 + 4);
        unsigned nk0 = ((const unsigned*)(mrow + scn + quad * 8))[0];
        unsigned nk1 = ((const unsigned*)(mrow + scn + quad * 8))[1];
        unsigned nk2 = ((const unsigned*)(mrow + scn + 32 + quad * 8))[0];
        unsigned nk3 = ((const unsigned*)(mrow + scn + 32 + quad * 8))[1];

        // add gauss / apply mask in A-domain
        #pragma unroll
        for (int j = 0; j < 4; j++) {
            s0[j] = ((mk0 >> (8 * j)) & 0xffu) ? -3e38f : (s0[j] + g0[j]);
            s1[j] = ((mk1 >> (8 * j)) & 0xffu) ? -3e38f : (s1[j] + g1[j]);
            s2[j] = ((mk2 >> (8 * j)) & 0xffu) ? -3e38f : (s2[j] + g2[j]);
            s3[j] = ((mk3 >> (8 * j)) & 0xffu) ? -3e38f : (s3[j] + g3[j]);
        }

        // row max: 15 local + 2 shfl (row spans the 4 quads)
        float mxa = fmaxf(fmaxf(fmaxf(s0[0], s0[1]), fmaxf(s0[2], s0[3])),
                          fmaxf(fmaxf(s1[0], s1[1]), fmaxf(s1[2], s1[3])));
        float mxb = fmaxf(fmaxf(fmaxf(s2[0], s2[1]), fmaxf(s2[2], s2[3])),
                          fmaxf(fmaxf(s3[0], s3[1]), fmaxf(s3[2], s3[3])));
        float mx = fmaxf(mxa, mxb);
        mx = fmaxf(mx, __shfl_xor(mx, 16, 64));
        mx = fmaxf(mx, __shfl_xor(mx, 32, 64));

        // defer-max: only rescale when the wave's max grew by > 8
        if (!__all(mx <= mr + 8.f)) {
            float nm = fmaxf(mr, mx);
            float al = __expf(mr - nm);
            mr = nm;
            ls *= al;
            int albits = __float_as_int(al);
            #pragma unroll
            for (int r = 0; r < 4; r++) {
                float alr = __int_as_float(
                    __builtin_amdgcn_ds_bpermute(4 * (quad * 4 + r), albits));
                o0[r] *= alr;
                o1[r] *= alr;
            }
        }

        float p[16];
        #pragma unroll
        for (int j = 0; j < 4; j++) {
            p[j]      = __expf(s0[j] - mr);
            p[4 + j]  = __expf(s1[j] - mr);
            p[8 + j]  = __expf(s2[j] - mr);
            p[12 + j] = __expf(s3[j] - mr);
        }
        float sm = 0.f;
        #pragma unroll
        for (int j = 0; j < 16; j++) sm += p[j];
        sm += __shfl_xor(sm, 16, 64);
        sm += __shfl_xor(sm, 32, 64);
        ls += sm;

        // pack P to bf16 A-fragments in-register
        short8 pa0, pa1;
        #pragma unroll
        for (int j = 0; j < 4; j++) {
            pa0[j]     = f2bf(p[j]);
            pa0[4 + j] = f2bf(p[4 + j]);
            pa1[j]     = f2bf(p[8 + j]);
            pa1[4 + j] = f2bf(p[12 + j]);
        }

        o0 = MFMA16(pa0, vb[0][0], o0);
        o0 = MFMA16(pa1, vb[0][1], o0);
        o1 = MFMA16(pa0, vb[1][0], o1);
        o1 = MFMA16(pa1, vb[1][1], o1);

        // rotate prefetched gauss/mask into current
        g0 = h0; g1 = h1; g2 = h2; g3 = h3;
        mk0 = nk0; mk1 = nk1; mk2 = nk2; mk3 = nk3;
    }

    // epilogue: reuse smem[wv] as 16x32 O-partial buffer
    asm volatile("s_waitcnt lgkmcnt(0)" ::: "memory");
    #pragma unroll
    for (int r = 0; r < 4; r++) {
        int row = quad * 4 + r;
        sl[row * 32 + l16]      = o0[r];
        sl[row * 32 + 16 + l16] = o1[r];
    }
    if (quad == 0) { mbuf[wv][l16] = mr; lbuf[wv][l16] = ls; }
    __syncthreads();

    // flash merge: thread = (row, col)
    int row = threadIdx.x >> 4, col = threadIdx.x & 15;
    float M = -3e38f;
    #pragma unroll
    for (int w = 0; w < 4; w++) M = fmaxf(M, mbuf[w][row]);
    float L = 0.f, a0 = 0.f, a1 = 0.f;
    #pragma unroll
    for (int w = 0; w < 4; w++) {
        float e = __expf(mbuf[w][row] - M);
        L += e * lbuf[w][row];
        a0 += e * smem[w][row * 32 + col];
        a1 += e * smem[w][row * 32 + 16 + col];
    }
    int l = lt * 16 + row;
    if (l < LQ) {
        float inv = 1.0f / L;
        size_t base = ((size_t)l * NB + n) * EE + h * DH;
        ows[base + col]      = f2bf(a0 * inv);
        ows[base + 16 + col] = f2bf(a1 * inv);
    }
}

// ---------------------------------------------------------------------------
// Output projection: wave = 16 tokens x 256 features, bf16 A/B, fp32 out
// ---------------------------------------------------------------------------
__global__ __launch_bounds__(256) void oproj_kernel(
    const short* __restrict__ xa, const short* __restrict__ wbf,
    const float* __restrict__ bias, float* __restrict__ out)
{
    int wave = (blockIdx.x * 256 + threadIdx.x) >> 6;
    int lid = threadIdx.x & 63, quad = lid >> 4, l16 = lid & 15;
    int t = wave * 16 + l16;

    const short* wb = wbf + 3 * EE * EE;
    f32x4 acc[16];
    #pragma unroll
    for (int f = 0; f < 16; f++) acc[f] = (f32x4){0.f, 0.f, 0.f, 0.f};

    for (int ks = 0; ks < 8; ks++) {
        short8 af = *(const short8*)(xa + (size_t)t * EE + ks * 32 + quad * 8);
        #pragma unroll
        for (int f = 0; f < 16; f++) {
            short8 bf = *(const short8*)(wb + (size_t)(f * 16 + l16) * EE + ks * 32 + quad * 8);
            acc[f] = MFMA16(af, bf, acc[f]);
        }
    }

    #pragma unroll
    for (int f = 0; f < 16; f++) {
        int e = f * 16 + l16;
        float bi = bias[e];
        #pragma unroll
        for (int r = 0; r < 4; r++) {
            int tok = wave * 16 + quad * 4 + r;
            out[(size_t)tok * EE + e] = acc[f][r] + bi;
        }
    }
}

extern "C" void kernel_launch(void* const* d_in, const int* in_sizes, int n_in,
                              void* d_out, int out_size, void* d_ws, size_t ws_size,
                              hipStream_t stream) {
    const float* query = (const float*)d_in[0];
    const float* key   = (const float*)d_in[1];
    const float* value = (const float*)d_in[2];
    const float* gauss = (const float*)d_in[3];
    const unsigned char* mask = (const unsigned char*)d_in[4];
    const float* ipw = (const float*)d_in[5];
    const float* ipb = (const float*)d_in[6];
    const float* opw = (const float*)d_in[7];
    const float* opb = (const float*)d_in[8];
    float* out = (float*)d_out;

    short* wbf = (short*)d_ws;                        // 262144 shorts
    short* qws = wbf + 4 * EE * EE;                   // 256*304*32
    short* kws = qws + (size_t)BH * LPAD * DH;        // 256*1024*32
    short* vws = kws + (size_t)BH * SK * DH;          // 256*1024*32
    short* vt  = vws + (size_t)BH * SK * DH;          // 256*32*1024
    short* ows = vt  + (size_t)BH * SK * DH;          // 9600*256

    prep_kernel<<<256, 256, 0, stream>>>(ipw, opw, wbf);
    proj_kernel<<<1174, 256, 0, stream>>>(query, key, value, wbf, ipb, qws, kws, vws);
    vtrans_kernel<<<1024, 256, 0, stream>>>(vws, vt);
    attn_kernel<<<BH * NLT, 256, 0, stream>>>(qws, kws, vt, gauss, mask, ows);
    oproj_kernel<<<150, 256, 0, stream>>>(ows, wbf, opb, out);
}